// Round 2
// baseline (381.014 us; speedup 1.0000x reference)
//
#include <hip/hip_runtime.h>
#include <hip/hip_cooperative_groups.h>

namespace cg = cooperative_groups;

#define LORA_SCALE 4.0f
#define ATT_SCALE 8.0f
#define NEG_SLOPE 0.2f
#define ELLW 64

typedef __attribute__((ext_vector_type(8))) short bf16x8;
typedef __attribute__((ext_vector_type(4))) float f32x4;
typedef unsigned short ushort_t;
typedef unsigned int uint_t;

__device__ inline ushort_t f2bf(float f) {
    uint_t u = __float_as_uint(f);
    u += 0x7fff + ((u >> 16) & 1);     // RNE
    return (ushort_t)(u >> 16);
}
__device__ inline float bf2f(ushort_t h) {
    return __uint_as_float(((uint_t)h) << 16);
}
__device__ inline void split_bf(float f, ushort_t& h, ushort_t& l) {
    h = f2bf(f);
    l = f2bf(f - bf2f(h));
}

struct MegaParams {
    const float *W0, *A0, *B0, *att_s0, *att_d0, *As0, *Bs0, *Ad0, *Bd0;
    const float *W1, *A1, *B1, *att_s1, *att_d1, *As1, *Bs1, *Ad1, *Bd1;
    const float *x;
    const int *ei;
    ushort_t *whi0, *wlo0, *whi1, *wlo1;
    ushort_t *xhi, *xlo, *hbhi, *hblo, *xpb;
    float *effS0, *effD0, *effS1, *effD1;
    float *ssrc, *sdst;
    int *cnt, *ell;
    float *out;
    int N, E_real, E_total, nTiles;
};

// ---------- MFMA GEMM tile phase (grid-stride over tiles) ----------
// 512 threads = 8 waves; wave w owns rows m0 = (tile>>2)*128 + w*16, cols n0=(tile&3)*64.
// B staged in MFMA-fragment order -> conflict-free ds_read_b128.
__device__ void gemm_phase(const ushort_t* __restrict__ Ahi, const ushort_t* __restrict__ Alo,
                           const ushort_t* __restrict__ Bhi, const ushort_t* __restrict__ Blo,
                           const float* __restrict__ effS, const float* __restrict__ effD,
                           ushort_t* __restrict__ Cb, float* __restrict__ ssrc,
                           float* __restrict__ sdst, int M, int nTiles,
                           ushort_t* sBh, ushort_t* sBl)
{
    const int K = 256;
    int tid = threadIdx.x;
    int w = tid >> 6;
    int lane = tid & 63;
    int quad = lane >> 4;
    int l16 = lane & 15;

    for (int tile = blockIdx.x; tile < nTiles; tile += gridDim.x) {
        int n0 = (tile & 3) * 64;
        int m0 = (tile >> 2) * 128 + w * 16;

        // ---- stage B-tile (64 rows x 256 K, hi+lo) into fragment-ordered LDS ----
        const ushort_t* srcH = Bhi + (size_t)n0 * K;
        const ushort_t* srcL = Blo + (size_t)n0 * K;
        #pragma unroll
        for (int c = 0; c < 4; c++) {
            int g  = c * 512 + tid;        // chunk id 0..2047 (8 shorts each)
            int rr = g >> 5;               // row 0..63
            int ch = g & 31;               // 8-short chunk within row
            int kblk = ch >> 2, qd = ch & 3;
            int tt = rr >> 4, l16r = rr & 15;
            int dst = (((tt * 8 + kblk) * 4 + qd) * 16 + l16r) * 8;
            *(bf16x8*)&sBh[dst] = *(const bf16x8*)(srcH + rr * K + ch * 8);
            *(bf16x8*)&sBl[dst] = *(const bf16x8*)(srcL + rr * K + ch * 8);
        }
        __syncthreads();

        int mr = m0 + l16; if (mr >= M) mr = M - 1;
        const ushort_t* ah = Ahi + mr * K + quad * 8;
        const ushort_t* al = Alo + mr * K + quad * 8;

        f32x4 acc[4] = {};
        #pragma unroll
        for (int kb = 0; kb < 8; kb++) {
            bf16x8 a_hi = *(const bf16x8*)(ah + kb * 32);
            bf16x8 a_lo = *(const bf16x8*)(al + kb * 32);
            #pragma unroll
            for (int t = 0; t < 4; t++) {
                int off = (((t * 8 + kb) * 4 + quad) * 16 + l16) * 8;
                bf16x8 b_hi = *(const bf16x8*)&sBh[off];
                bf16x8 b_lo = *(const bf16x8*)&sBl[off];
                acc[t] = __builtin_amdgcn_mfma_f32_16x16x32_bf16(a_hi, b_hi, acc[t], 0, 0, 0);
                acc[t] = __builtin_amdgcn_mfma_f32_16x16x32_bf16(a_hi, b_lo, acc[t], 0, 0, 0);
                acc[t] = __builtin_amdgcn_mfma_f32_16x16x32_bf16(a_lo, b_hi, acc[t], 0, 0, 0);
            }
        }

        // ---- store C as bf16: C/D layout col = l16, row = quad*4 + reg ----
        #pragma unroll
        for (int t = 0; t < 4; t++) {
            #pragma unroll
            for (int r = 0; r < 4; r++) {
                int m = m0 + quad * 4 + r;
                if (m < M) Cb[m * 256 + n0 + t * 16 + l16] = f2bf(acc[t][r]);
            }
        }

        // ---- fused scores (fp32, from accumulators) ----
        int h0 = n0 >> 5;
        float vs[2][4], vd[2][4];
        #pragma unroll
        for (int g = 0; g < 2; g++) {
            float e0s = effS[n0 + 32 * g + l16];
            float e1s = effS[n0 + 32 * g + 16 + l16];
            float e0d = effD[n0 + 32 * g + l16];
            float e1d = effD[n0 + 32 * g + 16 + l16];
            #pragma unroll
            for (int r = 0; r < 4; r++) {
                vs[g][r] = acc[2 * g][r] * e0s + acc[2 * g + 1][r] * e1s;
                vd[g][r] = acc[2 * g][r] * e0d + acc[2 * g + 1][r] * e1d;
            }
        }
        #pragma unroll
        for (int m = 1; m <= 8; m <<= 1) {
            #pragma unroll
            for (int g = 0; g < 2; g++)
                #pragma unroll
                for (int r = 0; r < 4; r++) {
                    vs[g][r] += __shfl_xor(vs[g][r], m);
                    vd[g][r] += __shfl_xor(vd[g][r], m);
                }
        }
        if (l16 == 0) {
            #pragma unroll
            for (int g = 0; g < 2; g++)
                #pragma unroll
                for (int r = 0; r < 4; r++) {
                    int m = m0 + quad * 4 + r;
                    if (m < M) {
                        ssrc[m * 8 + h0 + g] = vs[g][r];
                        sdst[m * 8 + h0 + g] = vd[g][r];
                    }
                }
        }
        __syncthreads();   // protect LDS before next tile's staging
    }
}

// ---------- gather-aggregate phase: 2 edges/wave-step, 16B loads ----------
// one wave per node; grid-stride over groups of 8 nodes (8 waves/block).
// lanes 0-31 take edge 2p, lanes 32-63 take edge 2p+1; each lane covers
// 8 channels (one bf16x8 = 16B load).
// mode 1: ELU -> bf16 hi/lo 256ch; mode 2: head-mean -> 32ch fp32
__device__ void agg_phase(const int* __restrict__ cnt, const int* __restrict__ ell,
                          const ushort_t* __restrict__ xpb,
                          const float* __restrict__ ssrc, const float* __restrict__ sdst,
                          float* __restrict__ out, ushort_t* __restrict__ ohi,
                          ushort_t* __restrict__ olo, int N, int mode, int* sidx)
{
    int w = threadIdx.x >> 6;
    int lane = threadIdx.x & 63;
    int eo = lane >> 5;          // which edge of the pair this half-wave owns
    int l32 = lane & 31;         // channel-chunk id: ch = l32*8 .. +8
    int h = l32 >> 2;            // head for these 8 channels
    int* srow = sidx + w * ELLW;
    int groups = (N + 7) >> 3;

    for (int g = blockIdx.x; g < groups; g += gridDim.x) {
        int d = g * 8 + w;       // wave-uniform
        if (d >= N) continue;
        float ssrc_h = ssrc[d * 8 + h];
        int end = cnt[d]; if (end > ELLW) end = ELLW;
        const int* row = ell + d * ELLW;
        // stage whole index row in LDS (per-wave region; no cross-wave sharing)
        srow[lane] = row[lane < end ? lane : 0];

        float acc[8] = {};
        float den = 0.f;
        for (int i = 0; i < end; i += 8) {   // 8 edges = 4 pair-steps per iter
            int idx[4];
            #pragma unroll
            for (int pp = 0; pp < 4; pp++) {
                int ii = i + 2 * pp + eo;
                idx[pp] = srow[ii < end ? ii : 0];
            }
            float t4[4];
            #pragma unroll
            for (int pp = 0; pp < 4; pp++) t4[pp] = sdst[idx[pp] * 8 + h];
            bf16x8 v[4];
            #pragma unroll
            for (int pp = 0; pp < 4; pp++)
                v[pp] = *(const bf16x8*)(xpb + idx[pp] * 256 + l32 * 8);
            #pragma unroll
            for (int pp = 0; pp < 4; pp++) {
                int ii = i + 2 * pp + eo;
                float al = ssrc_h + t4[pp];
                al = al > 0.f ? al : NEG_SLOPE * al;
                float wgt = (ii < end) ? __expf(al) : 0.f;
                den += wgt;
                #pragma unroll
                for (int j = 0; j < 8; j++)
                    acc[j] += bf2f((ushort_t)v[pp][j]) * wgt;
            }
        }
        // merge the two edge-halves (lanes l and l+32 hold the same channels)
        #pragma unroll
        for (int j = 0; j < 8; j++) acc[j] += __shfl_xor(acc[j], 32);
        den += __shfl_xor(den, 32);
        float inv = 1.f / den;
        #pragma unroll
        for (int j = 0; j < 8; j++) acc[j] *= inv;

        if (mode == 2) {
            #pragma unroll
            for (int m = 4; m <= 16; m <<= 1)
                #pragma unroll
                for (int j = 0; j < 8; j++) acc[j] += __shfl_xor(acc[j], m);
            if (lane < 4) {
                float4 r0 = { acc[0] * 0.125f, acc[1] * 0.125f, acc[2] * 0.125f, acc[3] * 0.125f };
                float4 r1 = { acc[4] * 0.125f, acc[5] * 0.125f, acc[6] * 0.125f, acc[7] * 0.125f };
                *(float4*)(out + d * 32 + l32 * 8) = r0;
                *(float4*)(out + d * 32 + l32 * 8 + 4) = r1;
            }
        } else {
            #pragma unroll
            for (int j = 0; j < 8; j++)
                acc[j] = acc[j] > 0.f ? acc[j] : (__expf(acc[j]) - 1.f);
            if (eo == 0) {
                ushort_t hs[8], ls[8];
                #pragma unroll
                for (int j = 0; j < 8; j++) split_bf(acc[j], hs[j], ls[j]);
                *(ushort4*)(ohi + d * 256 + l32 * 8)     = *(ushort4*)&hs[0];
                *(ushort4*)(ohi + d * 256 + l32 * 8 + 4) = *(ushort4*)&hs[4];
                *(ushort4*)(olo + d * 256 + l32 * 8)     = *(ushort4*)&ls[0];
                *(ushort4*)(olo + d * 256 + l32 * 8 + 4) = *(ushort4*)&ls[4];
            }
        }
    }
}

// ---------- single persistent cooperative kernel: all phases ----------
__global__ __launch_bounds__(512, 4) void mega(MegaParams p)
{
    __shared__ ushort_t sBh[16384];   // 32 KB: hi fragments (reused as sidx in agg)
    __shared__ ushort_t sBl[16384];   // 32 KB: lo fragments
    cg::grid_group grid = cg::this_grid();

    int tid = threadIdx.x;
    int gtid = blockIdx.x * 512 + tid;
    int gsize = gridDim.x * 512;
    int N = p.N;

    // ---- P0: weights + att-eff + x->bf16 split + cnt zero ----
    const int U0 = 131072;            // 2 layers x 65536 weight elems
    const int U1 = U0 + 512;          // 2 layers x 256 att-eff elems
    const int U2 = U1 + N * 32;       // x-split units (8 floats each)
    const int U3 = U2 + N;            // cnt zero
    for (int u = gtid; u < U3; u += gsize) {
        if (u < U0) {
            int layer = u >> 16;
            int i = u & 65535;
            const float* W = layer ? p.W1 : p.W0;
            const float* A = layer ? p.A1 : p.A0;
            const float* B = layer ? p.B1 : p.B0;
            int r = i >> 8, c = i & 255;
            float acc = W[i];
            #pragma unroll
            for (int k = 0; k < 8; k++) acc += LORA_SCALE * B[r * 8 + k] * A[k * 256 + c];
            ushort_t hh, ll;
            split_bf(acc, hh, ll);
            if (layer) { p.whi1[i] = hh; p.wlo1[i] = ll; }
            else       { p.whi0[i] = hh; p.wlo0[i] = ll; }
        } else if (u < U1) {
            int v = u - U0;           // 0..511
            int layer = v >> 8;
            int i = v & 255;
            int c2 = i & 31;
            const float* as_ = layer ? p.att_s1 : p.att_s0;
            const float* ad_ = layer ? p.att_d1 : p.att_d0;
            const float* As = layer ? p.As1 : p.As0;
            const float* Bs = layer ? p.Bs1 : p.Bs0;
            const float* Ad = layer ? p.Ad1 : p.Ad0;
            const float* Bd = layer ? p.Bd1 : p.Bd0;
            float es = as_[i], ed = ad_[i];
            #pragma unroll
            for (int k = 0; k < 4; k++) {
                es += ATT_SCALE * Bs[k] * As[k * 32 + c2];
                ed += ATT_SCALE * Bd[k] * Ad[k * 32 + c2];
            }
            if (layer) { p.effS1[i] = es; p.effD1[i] = ed; }
            else       { p.effS0[i] = es; p.effD0[i] = ed; }
        } else if (u < U2) {
            int i = u - U1;
            float4 v0 = *(const float4*)(p.x + (size_t)i * 8);
            float4 v1 = *(const float4*)(p.x + (size_t)i * 8 + 4);
            ushort4 h0, l0, h1, l1;
            split_bf(v0.x, h0.x, l0.x);
            split_bf(v0.y, h0.y, l0.y);
            split_bf(v0.z, h0.z, l0.z);
            split_bf(v0.w, h0.w, l0.w);
            split_bf(v1.x, h1.x, l1.x);
            split_bf(v1.y, h1.y, l1.y);
            split_bf(v1.z, h1.z, l1.z);
            split_bf(v1.w, h1.w, l1.w);
            *(ushort4*)(p.xhi + (size_t)i * 8)     = h0;
            *(ushort4*)(p.xhi + (size_t)i * 8 + 4) = h1;
            *(ushort4*)(p.xlo + (size_t)i * 8)     = l0;
            *(ushort4*)(p.xlo + (size_t)i * 8 + 4) = l1;
        } else {
            p.cnt[u - U2] = 0;
        }
    }
    grid.sync();

    // ---- P1: ELL fill (needs cnt zeroed) ----
    for (int e = gtid; e < p.E_total; e += gsize) {
        int s, d;
        if (e < p.E_real) { s = p.ei[e]; d = p.ei[p.E_real + e]; }
        else              { s = d = e - p.E_real; }
        int pos = atomicAdd(&p.cnt[d], 1);
        if (pos < ELLW) p.ell[d * ELLW + pos] = s;
    }
    grid.sync();

    // ---- layer 0 ----
    gemm_phase(p.xhi, p.xlo, p.whi0, p.wlo0, p.effS0, p.effD0,
               p.xpb, p.ssrc, p.sdst, N, p.nTiles, sBh, sBl);
    grid.sync();
    agg_phase(p.cnt, p.ell, p.xpb, p.ssrc, p.sdst,
              nullptr, p.hbhi, p.hblo, N, 1, (int*)sBh);
    grid.sync();

    // ---- layer 1 ----
    gemm_phase(p.hbhi, p.hblo, p.whi1, p.wlo1, p.effS1, p.effD1,
               p.xpb, p.ssrc, p.sdst, N, p.nTiles, sBh, sBl);
    grid.sync();
    agg_phase(p.cnt, p.ell, p.xpb, p.ssrc, p.sdst,
              p.out, nullptr, nullptr, N, 2, (int*)sBh);
}

extern "C" void kernel_launch(void* const* d_in, const int* in_sizes, int n_in,
                              void* d_out, int out_size, void* d_ws, size_t ws_size,
                              hipStream_t stream)
{
    MegaParams p;
    p.x  = (const float*)d_in[0];
    p.ei = (const int*)d_in[1];
    p.W0 = (const float*)d_in[2];
    p.A0 = (const float*)d_in[3];
    p.B0 = (const float*)d_in[4];
    p.att_s0 = (const float*)d_in[5];
    p.att_d0 = (const float*)d_in[6];
    p.As0 = (const float*)d_in[7];
    p.Bs0 = (const float*)d_in[8];
    p.Ad0 = (const float*)d_in[9];
    p.Bd0 = (const float*)d_in[10];
    p.W1 = (const float*)d_in[11];
    p.A1 = (const float*)d_in[12];
    p.B1 = (const float*)d_in[13];
    p.att_s1 = (const float*)d_in[14];
    p.att_d1 = (const float*)d_in[15];
    p.As1 = (const float*)d_in[16];
    p.Bs1 = (const float*)d_in[17];
    p.Ad1 = (const float*)d_in[18];
    p.Bd1 = (const float*)d_in[19];

    const int N = in_sizes[0] / 256;      // 10000
    const int E_real = in_sizes[1] / 2;   // 160000
    const int E_total = E_real + N;       // 170000

    // ---- workspace layout (unchanged) ----
    ushort_t* whi0 = (ushort_t*)d_ws;        // 65536 each
    ushort_t* wlo0 = whi0 + 65536;
    ushort_t* whi1 = wlo0 + 65536;
    ushort_t* wlo1 = whi1 + 65536;
    ushort_t* xhi  = wlo1 + 65536;           // N*256
    ushort_t* xlo  = xhi + 2560000;
    ushort_t* hbhi = xlo + 2560000;
    ushort_t* hblo = hbhi + 2560000;
    ushort_t* xpb  = hblo + 2560000;         // N*256 bf16 projected features
    float* effS0 = (float*)(xpb + 2560000);
    float* effD0 = effS0 + 256;
    float* effS1 = effD0 + 256;
    float* effD1 = effS1 + 256;
    float* ssrc  = effD1 + 256;              // N*8
    float* sdst  = ssrc + 80000;
    int* cnt = (int*)(sdst + 80000);         // N
    int* ell = cnt + 10016;                  // N*ELLW

    p.whi0 = whi0; p.wlo0 = wlo0; p.whi1 = whi1; p.wlo1 = wlo1;
    p.xhi = xhi; p.xlo = xlo; p.hbhi = hbhi; p.hblo = hblo; p.xpb = xpb;
    p.effS0 = effS0; p.effD0 = effD0; p.effS1 = effS1; p.effD1 = effD1;
    p.ssrc = ssrc; p.sdst = sdst; p.cnt = cnt; p.ell = ell;
    p.out = (float*)d_out;
    p.N = N; p.E_real = E_real; p.E_total = E_total;
    p.nTiles = 4 * ((N + 127) / 128);        // 316

    // co-residency-safe grid size for the cooperative launch
    int occ = 0;
    hipOccupancyMaxActiveBlocksPerMultiprocessor(&occ, (const void*)mega, 512, 0);
    if (occ < 1) occ = 1;
    int grid = occ * 256;                    // 256 CUs on MI355X
    if (grid > 512) grid = 512;

    void* args[] = { (void*)&p };
    hipLaunchCooperativeKernel((const void*)mega, dim3(grid), dim3(512), args, 0, stream);
}

// Round 3
// 182.655 us; speedup vs baseline: 2.0860x; 2.0860x over previous
//
#include <hip/hip_runtime.h>

#define LORA_SCALE 4.0f
#define ATT_SCALE 8.0f
#define NEG_SLOPE 0.2f
#define ELLW 64

typedef __attribute__((ext_vector_type(8))) short bf16x8;
typedef __attribute__((ext_vector_type(4))) float f32x4;
typedef unsigned short ushort_t;
typedef unsigned int uint_t;

__device__ inline ushort_t f2bf(float f) {
    uint_t u = __float_as_uint(f);
    u += 0x7fff + ((u >> 16) & 1);     // RNE
    return (ushort_t)(u >> 16);
}
__device__ inline float bf2f(ushort_t h) {
    return __uint_as_float(((uint_t)h) << 16);
}
__device__ inline void split_bf(float f, ushort_t& h, ushort_t& l) {
    h = f2bf(f);
    l = f2bf(f - bf2f(h));
}

// ---------- tiny standalone ELL fill (cnt zeroed by preceding gemm0) ----------
__global__ void ell_fill(const int* __restrict__ ei, int E_real, int E_total,
                         int* __restrict__ cnt, int* __restrict__ ell)
{
    int e = blockIdx.x * 256 + threadIdx.x;
    if (e >= E_total) return;
    int s, d;
    if (e < E_real) { s = ei[e]; d = ei[E_real + e]; }
    else            { s = d = e - E_real; }
    int pos = atomicAdd(&cnt[d], 1);
    if (pos < ELLW) ell[d * ELLW + pos] = s;
}

// ---------- self-contained MFMA GEMM + fused attention scores ----------
// MODE 0: A-operand = fp32 x, split to bf16 hi/lo in-register; also zeroes cnt.
// MODE 1: A-operand = bf16 hi/lo buffers (layer-1 input from agg0).
// B-tile = W + LORA_SCALE*B·A computed per block in fp32, split, staged in
// MFMA-fragment order in LDS (conflict-free ds_read_b128).
// block = 512 threads = 8 waves; wave w owns rows m0 = by*128 + w*16, cols n0 = bx*64.
// grid = (4, ceil(M/128))
template<int MODE>
__global__ __launch_bounds__(512, 4) void gemm_fused(
    const float* __restrict__ Xf,
    const ushort_t* __restrict__ Ahi, const ushort_t* __restrict__ Alo,
    const float* __restrict__ W, const float* __restrict__ Alora,
    const float* __restrict__ Blora,
    const float* __restrict__ att_s, const float* __restrict__ att_d,
    const float* __restrict__ As, const float* __restrict__ Bs,
    const float* __restrict__ Ad, const float* __restrict__ Bd,
    ushort_t* __restrict__ Cb, float* __restrict__ ssrc, float* __restrict__ sdst,
    int* __restrict__ cnt, int M)
{
    __shared__ ushort_t sBh[16384];   // 32 KB: hi fragments
    __shared__ ushort_t sBl[16384];   // 32 KB: lo fragments
    const int K = 256;
    int tid = threadIdx.x;
    int n0 = blockIdx.x * 64;

    if (MODE == 0) {
        // zero cnt for the downstream ell_fill dispatch (free here)
        int bid = blockIdx.y * 4 + blockIdx.x;
        if (bid < 40) {
            int i = bid * 256 + tid;
            if (i < 10240) cnt[i] = 0;
        }
    }

    // ---- compute B-tile Weff = W + LORA_SCALE*B·A, split, stage in frag order ----
    // chunk g = (rr, ch): row rr (0..63), 8 consecutive k at ch*8
    #pragma unroll
    for (int c = 0; c < 4; c++) {
        int g  = c * 512 + tid;        // 0..2047
        int rr = g >> 5;
        int ch = g & 31;
        int gr = n0 + rr;
        const float* wrow = W + gr * 256 + ch * 8;
        const float* brow = Blora + gr * 8;
        float a8[8];
        #pragma unroll
        for (int j = 0; j < 8; j++) a8[j] = wrow[j];
        #pragma unroll
        for (int k = 0; k < 8; k++) {
            float bv = LORA_SCALE * brow[k];
            const float* arow = Alora + k * 256 + ch * 8;
            #pragma unroll
            for (int j = 0; j < 8; j++) a8[j] += bv * arow[j];
        }
        bf16x8 vh, vl;
        #pragma unroll
        for (int j = 0; j < 8; j++) {
            ushort_t hh, ll;
            split_bf(a8[j], hh, ll);
            vh[j] = (short)hh;
            vl[j] = (short)ll;
        }
        int kblk = ch >> 2, qd = ch & 3;
        int tt = rr >> 4, l16r = rr & 15;
        int dst = (((tt * 8 + kblk) * 4 + qd) * 16 + l16r) * 8;
        *(bf16x8*)&sBh[dst] = vh;
        *(bf16x8*)&sBl[dst] = vl;
    }
    __syncthreads();

    int w = tid >> 6;
    int lane = tid & 63;
    int quad = lane >> 4;
    int l16 = lane & 15;
    int m0 = blockIdx.y * 128 + w * 16;
    int mr = m0 + l16; if (mr >= M) mr = M - 1;

    const float* xrow = (MODE == 0) ? (Xf + (size_t)mr * K + quad * 8) : nullptr;
    const ushort_t* ah = (MODE == 1) ? (Ahi + (size_t)mr * K + quad * 8) : nullptr;
    const ushort_t* al = (MODE == 1) ? (Alo + (size_t)mr * K + quad * 8) : nullptr;

    f32x4 acc[4] = {};
    #pragma unroll
    for (int kb = 0; kb < 8; kb++) {
        bf16x8 a_hi, a_lo;
        if (MODE == 0) {
            float4 f0 = *(const float4*)(xrow + kb * 32);
            float4 f1 = *(const float4*)(xrow + kb * 32 + 4);
            float fv[8] = { f0.x, f0.y, f0.z, f0.w, f1.x, f1.y, f1.z, f1.w };
            #pragma unroll
            for (int j = 0; j < 8; j++) {
                ushort_t hh, ll;
                split_bf(fv[j], hh, ll);
                a_hi[j] = (short)hh;
                a_lo[j] = (short)ll;
            }
        } else {
            a_hi = *(const bf16x8*)(ah + kb * 32);
            a_lo = *(const bf16x8*)(al + kb * 32);
        }
        #pragma unroll
        for (int t = 0; t < 4; t++) {
            int off = (((t * 8 + kb) * 4 + quad) * 16 + l16) * 8;
            bf16x8 b_hi = *(const bf16x8*)&sBh[off];
            bf16x8 b_lo = *(const bf16x8*)&sBl[off];
            acc[t] = __builtin_amdgcn_mfma_f32_16x16x32_bf16(a_hi, b_hi, acc[t], 0, 0, 0);
            acc[t] = __builtin_amdgcn_mfma_f32_16x16x32_bf16(a_hi, b_lo, acc[t], 0, 0, 0);
            acc[t] = __builtin_amdgcn_mfma_f32_16x16x32_bf16(a_lo, b_hi, acc[t], 0, 0, 0);
        }
    }

    // ---- store C as bf16: C/D layout col = l16, row = quad*4 + reg ----
    #pragma unroll
    for (int t = 0; t < 4; t++) {
        #pragma unroll
        for (int r = 0; r < 4; r++) {
            int m = m0 + quad * 4 + r;
            if (m < M) Cb[m * 256 + n0 + t * 16 + l16] = f2bf(acc[t][r]);
        }
    }

    // ---- fused scores (fp32, from accumulators); eff computed inline ----
    int h0 = n0 >> 5;
    float vs[2][4], vd[2][4];
    #pragma unroll
    for (int g = 0; g < 2; g++) {
        int cA = n0 + 32 * g + l16;
        float e0s = att_s[cA],      e0d = att_d[cA];
        float e1s = att_s[cA + 16], e1d = att_d[cA + 16];
        #pragma unroll
        for (int k = 0; k < 4; k++) {
            e0s += ATT_SCALE * Bs[k] * As[k * 32 + l16];
            e1s += ATT_SCALE * Bs[k] * As[k * 32 + 16 + l16];
            e0d += ATT_SCALE * Bd[k] * Ad[k * 32 + l16];
            e1d += ATT_SCALE * Bd[k] * Ad[k * 32 + 16 + l16];
        }
        #pragma unroll
        for (int r = 0; r < 4; r++) {
            vs[g][r] = acc[2 * g][r] * e0s + acc[2 * g + 1][r] * e1s;
            vd[g][r] = acc[2 * g][r] * e0d + acc[2 * g + 1][r] * e1d;
        }
    }
    #pragma unroll
    for (int m = 1; m <= 8; m <<= 1) {
        #pragma unroll
        for (int g = 0; g < 2; g++)
            #pragma unroll
            for (int r = 0; r < 4; r++) {
                vs[g][r] += __shfl_xor(vs[g][r], m);
                vd[g][r] += __shfl_xor(vd[g][r], m);
            }
    }
    if (l16 == 0) {
        #pragma unroll
        for (int g = 0; g < 2; g++)
            #pragma unroll
            for (int r = 0; r < 4; r++) {
                int m = m0 + quad * 4 + r;
                if (m < M) {
                    ssrc[m * 8 + h0 + g] = vs[g][r];
                    sdst[m * 8 + h0 + g] = vd[g][r];
                }
            }
    }
}

// ---------- gather-aggregate over ELL: 2 edges/wave-step, 16B loads ----------
// one wave per node. lanes 0-31 take edge 2p, lanes 32-63 take edge 2p+1;
// each lane covers 8 channels (one bf16x8 = 16B load).
// mode 1: ELU -> bf16 hi/lo 256ch; mode 2: head-mean -> 32ch fp32
__global__ __launch_bounds__(256) void ell_agg(const int* __restrict__ cnt,
                                               const int* __restrict__ ell,
                                               const ushort_t* __restrict__ xpb,
                                               const float* __restrict__ ssrc,
                                               const float* __restrict__ sdst,
                                               float* __restrict__ out,
                                               ushort_t* __restrict__ ohi,
                                               ushort_t* __restrict__ olo,
                                               int N, int mode)
{
    __shared__ int sidx[4][ELLW];
    int gid = blockIdx.x * blockDim.x + threadIdx.x;
    int d = gid >> 6;
    if (d >= N) return;
    int w = threadIdx.x >> 6;
    int lane = threadIdx.x & 63;
    int eo = lane >> 5;          // which edge of the pair this half-wave owns
    int l32 = lane & 31;         // channel-chunk id: ch = l32*8 .. +8
    int h = l32 >> 2;            // head for these 8 channels
    float ssrc_h = ssrc[d * 8 + h];
    int end = cnt[d]; if (end > ELLW) end = ELLW;
    const int* row = ell + d * ELLW;
    sidx[w][lane] = row[lane < end ? lane : 0];

    float acc[8] = {};
    float den = 0.f;
    for (int i = 0; i < end; i += 8) {       // 8 edges = 4 pair-steps per iter
        int idx[4];
        #pragma unroll
        for (int pp = 0; pp < 4; pp++) {
            int ii = i + 2 * pp + eo;
            idx[pp] = sidx[w][ii < end ? ii : 0];
        }
        float t4[4];
        #pragma unroll
        for (int pp = 0; pp < 4; pp++) t4[pp] = sdst[idx[pp] * 8 + h];
        bf16x8 v[4];
        #pragma unroll
        for (int pp = 0; pp < 4; pp++)
            v[pp] = *(const bf16x8*)(xpb + idx[pp] * 256 + l32 * 8);
        #pragma unroll
        for (int pp = 0; pp < 4; pp++) {
            int ii = i + 2 * pp + eo;
            float al = ssrc_h + t4[pp];
            al = al > 0.f ? al : NEG_SLOPE * al;
            float wgt = (ii < end) ? __expf(al) : 0.f;
            den += wgt;
            #pragma unroll
            for (int j = 0; j < 8; j++)
                acc[j] += bf2f((ushort_t)v[pp][j]) * wgt;
        }
    }
    // merge the two edge-halves (lanes l and l+32 hold the same channels)
    #pragma unroll
    for (int j = 0; j < 8; j++) acc[j] += __shfl_xor(acc[j], 32);
    den += __shfl_xor(den, 32);
    float inv = 1.f / den;
    #pragma unroll
    for (int j = 0; j < 8; j++) acc[j] *= inv;

    if (mode == 2) {
        #pragma unroll
        for (int m = 4; m <= 16; m <<= 1)
            #pragma unroll
            for (int j = 0; j < 8; j++) acc[j] += __shfl_xor(acc[j], m);
        if (lane < 4) {
            float4 r0 = { acc[0] * 0.125f, acc[1] * 0.125f, acc[2] * 0.125f, acc[3] * 0.125f };
            float4 r1 = { acc[4] * 0.125f, acc[5] * 0.125f, acc[6] * 0.125f, acc[7] * 0.125f };
            *(float4*)(out + d * 32 + l32 * 8) = r0;
            *(float4*)(out + d * 32 + l32 * 8 + 4) = r1;
        }
        return;
    }
    #pragma unroll
    for (int j = 0; j < 8; j++)
        acc[j] = acc[j] > 0.f ? acc[j] : (__expf(acc[j]) - 1.f);
    if (eo == 0) {
        ushort_t hs[8], ls[8];
        #pragma unroll
        for (int j = 0; j < 8; j++) split_bf(acc[j], hs[j], ls[j]);
        *(ushort4*)(ohi + d * 256 + l32 * 8)     = *(ushort4*)&hs[0];
        *(ushort4*)(ohi + d * 256 + l32 * 8 + 4) = *(ushort4*)&hs[4];
        *(ushort4*)(olo + d * 256 + l32 * 8)     = *(ushort4*)&ls[0];
        *(ushort4*)(olo + d * 256 + l32 * 8 + 4) = *(ushort4*)&ls[4];
    }
}

extern "C" void kernel_launch(void* const* d_in, const int* in_sizes, int n_in,
                              void* d_out, int out_size, void* d_ws, size_t ws_size,
                              hipStream_t stream)
{
    const float* x  = (const float*)d_in[0];
    const int*   ei = (const int*)d_in[1];
    const float* W0 = (const float*)d_in[2];
    const float* A0 = (const float*)d_in[3];
    const float* B0 = (const float*)d_in[4];
    const float* att_s0 = (const float*)d_in[5];
    const float* att_d0 = (const float*)d_in[6];
    const float* As0 = (const float*)d_in[7];
    const float* Bs0 = (const float*)d_in[8];
    const float* Ad0 = (const float*)d_in[9];
    const float* Bd0 = (const float*)d_in[10];
    const float* W1 = (const float*)d_in[11];
    const float* A1 = (const float*)d_in[12];
    const float* B1 = (const float*)d_in[13];
    const float* att_s1 = (const float*)d_in[14];
    const float* att_d1 = (const float*)d_in[15];
    const float* As1 = (const float*)d_in[16];
    const float* Bs1 = (const float*)d_in[17];
    const float* Ad1 = (const float*)d_in[18];
    const float* Bd1 = (const float*)d_in[19];

    const int N = in_sizes[0] / 256;      // 10000
    const int E_real = in_sizes[1] / 2;   // 160000
    const int E_total = E_real + N;       // 170000

    // ---- workspace layout ----
    ushort_t* hbhi = (ushort_t*)d_ws;        // N*256 each
    ushort_t* hblo = hbhi + 2560000;
    ushort_t* xpb  = hblo + 2560000;         // N*256 bf16 projected features
    float* ssrc = (float*)(xpb + 2560000);   // N*8
    float* sdst = ssrc + 80000;
    int* cnt = (int*)(sdst + 80000);         // 10240
    int* ell = cnt + 10240;                  // N*ELLW

    dim3 gg(4, (N + 127) / 128);
    int fillB = (E_total + 255) / 256;
    int aggBlocks = (N * 64 + 255) / 256;

    // ---------------- layer 0 (gemm0 also zeroes cnt) ----------------
    gemm_fused<0><<<gg, 512, 0, stream>>>(
        x, nullptr, nullptr,
        W0, A0, B0, att_s0, att_d0, As0, Bs0, Ad0, Bd0,
        xpb, ssrc, sdst, cnt, N);
    ell_fill<<<fillB, 256, 0, stream>>>(ei, E_real, E_total, cnt, ell);
    ell_agg<<<aggBlocks, 256, 0, stream>>>(cnt, ell, xpb, ssrc, sdst,
                                           nullptr, hbhi, hblo, N, 1);

    // ---------------- layer 1 ----------------
    gemm_fused<1><<<gg, 512, 0, stream>>>(
        nullptr, hbhi, hblo,
        W1, A1, B1, att_s1, att_d1, As1, Bs1, Ad1, Bd1,
        xpb, ssrc, sdst, nullptr, N);
    ell_agg<<<aggBlocks, 256, 0, stream>>>(cnt, ell, xpb, ssrc, sdst,
                                           (float*)d_out, nullptr, nullptr, N, 2);
}

// Round 4
// 172.032 us; speedup vs baseline: 2.2148x; 1.0618x over previous
//
#include <hip/hip_runtime.h>

#define LORA_SCALE 4.0f
#define ATT_SCALE 8.0f
#define NEG_SLOPE 0.2f
#define ELLW 64

typedef __attribute__((ext_vector_type(8))) short bf16x8;
typedef __attribute__((ext_vector_type(4))) float f32x4;
typedef unsigned short ushort_t;
typedef unsigned int uint_t;

__device__ inline ushort_t f2bf(float f) {
    uint_t u = __float_as_uint(f);
    u += 0x7fff + ((u >> 16) & 1);     // RNE
    return (ushort_t)(u >> 16);
}
__device__ inline float bf2f(ushort_t h) {
    return __uint_as_float(((uint_t)h) << 16);
}
__device__ inline void split_bf(float f, ushort_t& h, ushort_t& l) {
    h = f2bf(f);
    l = f2bf(f - bf2f(h));
}

// ---------- fused prep: weights(2 layers) + x->bf16 split + ELL fill ----------
// grid-stride over flat unit space; 1024-thr blocks to minimize WG count.
// requires cnt[] zeroed beforehand (hipMemsetAsync)
__global__ __launch_bounds__(1024) void prep_all(
    const float* __restrict__ W0, const float* __restrict__ A0,
    const float* __restrict__ B0,
    const float* __restrict__ att_s0, const float* __restrict__ att_d0,
    const float* __restrict__ As0, const float* __restrict__ Bs0,
    const float* __restrict__ Ad0, const float* __restrict__ Bd0,
    const float* __restrict__ W1, const float* __restrict__ A1,
    const float* __restrict__ B1,
    const float* __restrict__ att_s1, const float* __restrict__ att_d1,
    const float* __restrict__ As1, const float* __restrict__ Bs1,
    const float* __restrict__ Ad1, const float* __restrict__ Bd1,
    ushort_t* __restrict__ whi0, ushort_t* __restrict__ wlo0,
    ushort_t* __restrict__ whi1, ushort_t* __restrict__ wlo1,
    float* __restrict__ effS0, float* __restrict__ effD0,
    float* __restrict__ effS1, float* __restrict__ effD1,
    const float* __restrict__ x, ushort_t* __restrict__ xhi,
    ushort_t* __restrict__ xlo,
    const int* __restrict__ ei, int E_real, int E_total,
    int* __restrict__ cnt, int* __restrict__ ell, int N)
{
    const int U_W   = 131072;            // 2 layers x 65536 weight elems
    const int U_EFF = U_W + 512;         // 2 layers x 256 att-eff elems
    const int U_CONV = U_EFF + N * 32;   // x-split units (8 floats each)
    const int U_FILL = U_CONV + E_total; // ELL fill units

    for (int u = blockIdx.x * 1024 + threadIdx.x; u < U_FILL;
         u += gridDim.x * 1024) {
        if (u < U_W) {
            int layer = u >> 16;
            int i = u & 65535;
            const float* W = layer ? W1 : W0;
            const float* A = layer ? A1 : A0;
            const float* B = layer ? B1 : B0;
            int r = i >> 8, c = i & 255;
            float acc = W[i];
            #pragma unroll
            for (int k = 0; k < 8; k++) acc += LORA_SCALE * B[r * 8 + k] * A[k * 256 + c];
            ushort_t h, l;
            split_bf(acc, h, l);
            if (layer) { whi1[i] = h; wlo1[i] = l; }
            else       { whi0[i] = h; wlo0[i] = l; }
        } else if (u < U_EFF) {
            int v = u - U_W;             // 0..511
            int layer = v >> 8;
            int i = v & 255;
            int c2 = i & 31;
            const float* as_ = layer ? att_s1 : att_s0;
            const float* ad_ = layer ? att_d1 : att_d0;
            const float* As = layer ? As1 : As0;
            const float* Bs = layer ? Bs1 : Bs0;
            const float* Ad = layer ? Ad1 : Ad0;
            const float* Bd = layer ? Bd1 : Bd0;
            float es = as_[i], ed = ad_[i];
            #pragma unroll
            for (int k = 0; k < 4; k++) {
                es += ATT_SCALE * Bs[k] * As[k * 32 + c2];
                ed += ATT_SCALE * Bd[k] * Ad[k * 32 + c2];
            }
            if (layer) { effS1[i] = es; effD1[i] = ed; }
            else       { effS0[i] = es; effD0[i] = ed; }
        } else if (u < U_CONV) {
            int i = u - U_EFF;
            float4 v0 = *(const float4*)(x + (size_t)i * 8);
            float4 v1 = *(const float4*)(x + (size_t)i * 8 + 4);
            ushort4 h0, l0, h1, l1;
            split_bf(v0.x, h0.x, l0.x);
            split_bf(v0.y, h0.y, l0.y);
            split_bf(v0.z, h0.z, l0.z);
            split_bf(v0.w, h0.w, l0.w);
            split_bf(v1.x, h1.x, l1.x);
            split_bf(v1.y, h1.y, l1.y);
            split_bf(v1.z, h1.z, l1.z);
            split_bf(v1.w, h1.w, l1.w);
            *(ushort4*)(xhi + (size_t)i * 8)     = h0;
            *(ushort4*)(xhi + (size_t)i * 8 + 4) = h1;
            *(ushort4*)(xlo + (size_t)i * 8)     = l0;
            *(ushort4*)(xlo + (size_t)i * 8 + 4) = l1;
        } else {
            int e = u - U_CONV;
            int s, d;
            if (e < E_real) { s = ei[e]; d = ei[E_real + e]; }
            else            { s = d = e - E_real; }
            int pos = atomicAdd(&cnt[d], 1);
            if (pos < ELLW) ell[d * ELLW + pos] = s;
        }
    }
}

// ---------- MFMA GEMM + fused attention scores; B-tile staged in LDS ----------
// block = 512 threads = 8 waves sharing one 64-col n-tile; wave w owns rows
// m0 = by*128 + w*16. B staged in MFMA-fragment order -> conflict-free ds_read_b128.
// grid = (4, ceil(M/128))
__global__ __launch_bounds__(512) void gemm_fused(
    const ushort_t* __restrict__ Ahi, const ushort_t* __restrict__ Alo,
    const ushort_t* __restrict__ Bhi, const ushort_t* __restrict__ Blo,
    const float* __restrict__ effS, const float* __restrict__ effD,
    ushort_t* __restrict__ Cb, float* __restrict__ ssrc, float* __restrict__ sdst, int M)
{
    __shared__ ushort_t sBh[16384];   // 32 KB: hi fragments
    __shared__ ushort_t sBl[16384];   // 32 KB: lo fragments
    const int K = 256;
    int tid = threadIdx.x;
    int n0 = blockIdx.x * 64;

    // ---- stage B-tile (64 rows x 256 K, hi+lo) into fragment-ordered LDS ----
    // fragment addr for (row rr, k): t=rr>>4, l16=rr&15, kblk=k>>5, quad=(k>>3)&3
    //   dst = (((t*8 + kblk)*4 + quad)*16 + l16)*8
    const ushort_t* srcH = Bhi + (size_t)n0 * K;
    const ushort_t* srcL = Blo + (size_t)n0 * K;
    #pragma unroll
    for (int c = 0; c < 4; c++) {
        int g  = c * 512 + tid;        // chunk id 0..2047 (8 shorts each)
        int rr = g >> 5;               // row 0..63
        int ch = g & 31;               // 8-short chunk within row
        int kblk = ch >> 2, quad = ch & 3;
        int tt = rr >> 4, l16r = rr & 15;
        int dst = (((tt * 8 + kblk) * 4 + quad) * 16 + l16r) * 8;
        *(bf16x8*)&sBh[dst] = *(const bf16x8*)(srcH + rr * K + ch * 8);
        *(bf16x8*)&sBl[dst] = *(const bf16x8*)(srcL + rr * K + ch * 8);
    }
    __syncthreads();

    int w = tid >> 6;
    int lane = tid & 63;
    int quad = lane >> 4;
    int l16 = lane & 15;
    int m0 = blockIdx.y * 128 + w * 16;
    int mr = m0 + l16; if (mr >= M) mr = M - 1;

    const ushort_t* ah = Ahi + mr * K + quad * 8;
    const ushort_t* al = Alo + mr * K + quad * 8;

    f32x4 acc[4] = {};
    #pragma unroll
    for (int kb = 0; kb < 8; kb++) {
        bf16x8 a_hi = *(const bf16x8*)(ah + kb * 32);
        bf16x8 a_lo = *(const bf16x8*)(al + kb * 32);
        #pragma unroll
        for (int t = 0; t < 4; t++) {
            int off = (((t * 8 + kb) * 4 + quad) * 16 + l16) * 8;
            bf16x8 b_hi = *(const bf16x8*)&sBh[off];
            bf16x8 b_lo = *(const bf16x8*)&sBl[off];
            acc[t] = __builtin_amdgcn_mfma_f32_16x16x32_bf16(a_hi, b_hi, acc[t], 0, 0, 0);
            acc[t] = __builtin_amdgcn_mfma_f32_16x16x32_bf16(a_hi, b_lo, acc[t], 0, 0, 0);
            acc[t] = __builtin_amdgcn_mfma_f32_16x16x32_bf16(a_lo, b_hi, acc[t], 0, 0, 0);
        }
    }

    // ---- store C as bf16: C/D layout col = l16, row = quad*4 + reg ----
    #pragma unroll
    for (int t = 0; t < 4; t++) {
        #pragma unroll
        for (int r = 0; r < 4; r++) {
            int m = m0 + quad * 4 + r;
            if (m < M) Cb[m * 256 + n0 + t * 16 + l16] = f2bf(acc[t][r]);
        }
    }

    // ---- fused scores (fp32, from accumulators) ----
    int h0 = n0 >> 5;
    float vs[2][4], vd[2][4];
    #pragma unroll
    for (int g = 0; g < 2; g++) {
        float e0s = effS[n0 + 32 * g + l16];
        float e1s = effS[n0 + 32 * g + 16 + l16];
        float e0d = effD[n0 + 32 * g + l16];
        float e1d = effD[n0 + 32 * g + 16 + l16];
        #pragma unroll
        for (int r = 0; r < 4; r++) {
            vs[g][r] = acc[2 * g][r] * e0s + acc[2 * g + 1][r] * e1s;
            vd[g][r] = acc[2 * g][r] * e0d + acc[2 * g + 1][r] * e1d;
        }
    }
    #pragma unroll
    for (int m = 1; m <= 8; m <<= 1) {
        #pragma unroll
        for (int g = 0; g < 2; g++)
            #pragma unroll
            for (int r = 0; r < 4; r++) {
                vs[g][r] += __shfl_xor(vs[g][r], m);
                vd[g][r] += __shfl_xor(vd[g][r], m);
            }
    }
    if (l16 == 0) {
        #pragma unroll
        for (int g = 0; g < 2; g++)
            #pragma unroll
            for (int r = 0; r < 4; r++) {
                int m = m0 + quad * 4 + r;
                if (m < M) {
                    ssrc[m * 8 + h0 + g] = vs[g][r];
                    sdst[m * 8 + h0 + g] = vd[g][r];
                }
            }
    }
}

// ---------- gather-aggregate over ELL: 2 edges/wave-step, 16B loads ----------
// one wave per node; 1024-thr blocks (16 waves) to minimize WG count.
// lanes 0-31 take edge 2p, lanes 32-63 take edge 2p+1; each lane covers
// 8 channels (one bf16x8 = 16B load).
// mode 1: ELU -> bf16 hi/lo 256ch; mode 2: head-mean -> 32ch fp32
__global__ __launch_bounds__(1024) void ell_agg(const int* __restrict__ cnt,
                                                const int* __restrict__ ell,
                                                const ushort_t* __restrict__ xpb,
                                                const float* __restrict__ ssrc,
                                                const float* __restrict__ sdst,
                                                float* __restrict__ out,
                                                ushort_t* __restrict__ ohi,
                                                ushort_t* __restrict__ olo,
                                                int N, int mode)
{
    __shared__ int sidx[16][ELLW];
    int gid = blockIdx.x * blockDim.x + threadIdx.x;
    int d = gid >> 6;
    if (d >= N) return;
    int w = threadIdx.x >> 6;
    int lane = threadIdx.x & 63;
    int eo = lane >> 5;          // which edge of the pair this half-wave owns
    int l32 = lane & 31;         // channel-chunk id: ch = l32*8 .. +8
    int h = l32 >> 2;            // head for these 8 channels
    float ssrc_h = ssrc[d * 8 + h];
    int end = cnt[d]; if (end > ELLW) end = ELLW;
    const int* row = ell + d * ELLW;
    sidx[w][lane] = row[lane < end ? lane : 0];

    float acc[8] = {};
    float den = 0.f;
    for (int i = 0; i < end; i += 8) {       // 8 edges = 4 pair-steps per iter
        int idx[4];
        #pragma unroll
        for (int pp = 0; pp < 4; pp++) {
            int ii = i + 2 * pp + eo;
            idx[pp] = sidx[w][ii < end ? ii : 0];
        }
        float t4[4];
        #pragma unroll
        for (int pp = 0; pp < 4; pp++) t4[pp] = sdst[idx[pp] * 8 + h];
        bf16x8 v[4];
        #pragma unroll
        for (int pp = 0; pp < 4; pp++)
            v[pp] = *(const bf16x8*)(xpb + idx[pp] * 256 + l32 * 8);
        #pragma unroll
        for (int pp = 0; pp < 4; pp++) {
            int ii = i + 2 * pp + eo;
            float al = ssrc_h + t4[pp];
            al = al > 0.f ? al : NEG_SLOPE * al;
            float wgt = (ii < end) ? __expf(al) : 0.f;
            den += wgt;
            #pragma unroll
            for (int j = 0; j < 8; j++)
                acc[j] += bf2f((ushort_t)v[pp][j]) * wgt;
        }
    }
    // merge the two edge-halves (lanes l and l+32 hold the same channels)
    #pragma unroll
    for (int j = 0; j < 8; j++) acc[j] += __shfl_xor(acc[j], 32);
    den += __shfl_xor(den, 32);
    float inv = 1.f / den;
    #pragma unroll
    for (int j = 0; j < 8; j++) acc[j] *= inv;

    if (mode == 2) {
        #pragma unroll
        for (int m = 4; m <= 16; m <<= 1)
            #pragma unroll
            for (int j = 0; j < 8; j++) acc[j] += __shfl_xor(acc[j], m);
        if (lane < 4) {
            float4 r0 = { acc[0] * 0.125f, acc[1] * 0.125f, acc[2] * 0.125f, acc[3] * 0.125f };
            float4 r1 = { acc[4] * 0.125f, acc[5] * 0.125f, acc[6] * 0.125f, acc[7] * 0.125f };
            *(float4*)(out + d * 32 + l32 * 8) = r0;
            *(float4*)(out + d * 32 + l32 * 8 + 4) = r1;
        }
        return;
    }
    #pragma unroll
    for (int j = 0; j < 8; j++)
        acc[j] = acc[j] > 0.f ? acc[j] : (__expf(acc[j]) - 1.f);
    if (eo == 0) {
        ushort_t hs[8], ls[8];
        #pragma unroll
        for (int j = 0; j < 8; j++) split_bf(acc[j], hs[j], ls[j]);
        *(ushort4*)(ohi + d * 256 + l32 * 8)     = *(ushort4*)&hs[0];
        *(ushort4*)(ohi + d * 256 + l32 * 8 + 4) = *(ushort4*)&hs[4];
        *(ushort4*)(olo + d * 256 + l32 * 8)     = *(ushort4*)&ls[0];
        *(ushort4*)(olo + d * 256 + l32 * 8 + 4) = *(ushort4*)&ls[4];
    }
}

extern "C" void kernel_launch(void* const* d_in, const int* in_sizes, int n_in,
                              void* d_out, int out_size, void* d_ws, size_t ws_size,
                              hipStream_t stream)
{
    const float* x  = (const float*)d_in[0];
    const int*   ei = (const int*)d_in[1];
    const float* W0 = (const float*)d_in[2];
    const float* A0 = (const float*)d_in[3];
    const float* B0 = (const float*)d_in[4];
    const float* att_s0 = (const float*)d_in[5];
    const float* att_d0 = (const float*)d_in[6];
    const float* As0 = (const float*)d_in[7];
    const float* Bs0 = (const float*)d_in[8];
    const float* Ad0 = (const float*)d_in[9];
    const float* Bd0 = (const float*)d_in[10];
    const float* W1 = (const float*)d_in[11];
    const float* A1 = (const float*)d_in[12];
    const float* B1 = (const float*)d_in[13];
    const float* att_s1 = (const float*)d_in[14];
    const float* att_d1 = (const float*)d_in[15];
    const float* As1 = (const float*)d_in[16];
    const float* Bs1 = (const float*)d_in[17];
    const float* Ad1 = (const float*)d_in[18];
    const float* Bd1 = (const float*)d_in[19];

    const int N = in_sizes[0] / 256;      // 10000
    const int E_real = in_sizes[1] / 2;   // 160000
    const int E_total = E_real + N;       // 170000

    // ---- workspace layout ----
    ushort_t* whi0 = (ushort_t*)d_ws;        // 65536 each
    ushort_t* wlo0 = whi0 + 65536;
    ushort_t* whi1 = wlo0 + 65536;
    ushort_t* wlo1 = whi1 + 65536;
    ushort_t* xhi  = wlo1 + 65536;           // N*256
    ushort_t* xlo  = xhi + 2560000;
    ushort_t* hbhi = xlo + 2560000;
    ushort_t* hblo = hbhi + 2560000;
    ushort_t* xpb  = hblo + 2560000;         // N*256 bf16 projected features
    float* effS0 = (float*)(xpb + 2560000);
    float* effD0 = effS0 + 256;
    float* effS1 = effD0 + 256;
    float* effD1 = effS1 + 256;
    float* ssrc  = effD1 + 256;              // N*8
    float* sdst  = ssrc + 80000;
    int* cnt = (int*)(sdst + 80000);         // N
    int* ell = cnt + 10016;                  // N*ELLW

    // ---- zero cnt, then fused prep (weights + x split + ELL fill) ----
    hipMemsetAsync(cnt, 0, (size_t)N * sizeof(int), stream);
    int totalUnits = 131072 + 512 + N * 32 + E_total;
    int prepB = (totalUnits + 1023) / 1024;
    if (prepB > 640) prepB = 640;
    prep_all<<<prepB, 1024, 0, stream>>>(
        W0, A0, B0, att_s0, att_d0, As0, Bs0, Ad0, Bd0,
        W1, A1, B1, att_s1, att_d1, As1, Bs1, Ad1, Bd1,
        whi0, wlo0, whi1, wlo1, effS0, effD0, effS1, effD1,
        x, xhi, xlo, ei, E_real, E_total, cnt, ell, N);

    dim3 gg(4, (N + 127) / 128);
    int aggBlocks = (N * 64 + 1023) / 1024;

    // ---------------- layer 0 ----------------
    gemm_fused<<<gg, 512, 0, stream>>>(xhi, xlo, whi0, wlo0, effS0, effD0, xpb, ssrc, sdst, N);
    ell_agg<<<aggBlocks, 1024, 0, stream>>>(cnt, ell, xpb, ssrc, sdst,
                                            nullptr, hbhi, hblo, N, 1);

    // ---------------- layer 1 ----------------
    gemm_fused<<<gg, 512, 0, stream>>>(hbhi, hblo, whi1, wlo1, effS1, effD1, xpb, ssrc, sdst, N);
    ell_agg<<<aggBlocks, 1024, 0, stream>>>(cnt, ell, xpb, ssrc, sdst,
                                            (float*)d_out, nullptr, nullptr, N, 2);
}

// Round 5
// 163.113 us; speedup vs baseline: 2.3359x; 1.0547x over previous
//
#include <hip/hip_runtime.h>

#define LORA_SCALE 4.0f
#define ATT_SCALE 8.0f
#define NEG_SLOPE 0.2f
#define ELLW 64

typedef __attribute__((ext_vector_type(8))) short bf16x8;
typedef __attribute__((ext_vector_type(4))) float f32x4;
typedef unsigned short ushort_t;
typedef unsigned int uint_t;

__device__ inline ushort_t f2bf(float f) {
    uint_t u = __float_as_uint(f);
    u += 0x7fff + ((u >> 16) & 1);     // RNE
    return (ushort_t)(u >> 16);
}
__device__ inline float bf2f(ushort_t h) {
    return __uint_as_float(((uint_t)h) << 16);
}
__device__ inline void split_bf(float f, ushort_t& h, ushort_t& l) {
    h = f2bf(f);
    l = f2bf(f - bf2f(h));
}

// ---------- fused prep: weights(2 layers) + x->bf16 split + cnt zero ----------
// (ELL fill moved into gemm0's tail; cnt zero here replaces the memset dispatch)
__global__ void prep_all(const float* __restrict__ W0, const float* __restrict__ A0,
                         const float* __restrict__ B0,
                         const float* __restrict__ att_s0, const float* __restrict__ att_d0,
                         const float* __restrict__ As0, const float* __restrict__ Bs0,
                         const float* __restrict__ Ad0, const float* __restrict__ Bd0,
                         const float* __restrict__ W1, const float* __restrict__ A1,
                         const float* __restrict__ B1,
                         const float* __restrict__ att_s1, const float* __restrict__ att_d1,
                         const float* __restrict__ As1, const float* __restrict__ Bs1,
                         const float* __restrict__ Ad1, const float* __restrict__ Bd1,
                         ushort_t* __restrict__ whi0, ushort_t* __restrict__ wlo0,
                         ushort_t* __restrict__ whi1, ushort_t* __restrict__ wlo1,
                         float* __restrict__ effS0, float* __restrict__ effD0,
                         float* __restrict__ effS1, float* __restrict__ effD1,
                         const float* __restrict__ x, ushort_t* __restrict__ xhi,
                         ushort_t* __restrict__ xlo,
                         int* __restrict__ cnt, int N)
{
    int b = blockIdx.x;
    int t = threadIdx.x;
    if (b < 512) {
        int layer = b >> 8;
        int i = (b & 255) * 256 + t;
        const float* W = layer ? W1 : W0;
        const float* A = layer ? A1 : A0;
        const float* B = layer ? B1 : B0;
        int r = i >> 8, c = i & 255;
        float acc = W[i];
        #pragma unroll
        for (int k = 0; k < 8; k++) acc += LORA_SCALE * B[r * 8 + k] * A[k * 256 + c];
        ushort_t h, l;
        split_bf(acc, h, l);
        if (layer) { whi1[i] = h; wlo1[i] = l; }
        else       { whi0[i] = h; wlo0[i] = l; }
        if (i < 256) {
            int c2 = i & 31;
            const float* as_ = layer ? att_s1 : att_s0;
            const float* ad_ = layer ? att_d1 : att_d0;
            const float* As = layer ? As1 : As0;
            const float* Bs = layer ? Bs1 : Bs0;
            const float* Ad = layer ? Ad1 : Ad0;
            const float* Bd = layer ? Bd1 : Bd0;
            float es = as_[i], ed = ad_[i];
            #pragma unroll
            for (int k = 0; k < 4; k++) {
                es += ATT_SCALE * Bs[k] * As[k * 32 + c2];
                ed += ATT_SCALE * Bd[k] * Ad[k * 32 + c2];
            }
            if (layer) { effS1[i] = es; effD1[i] = ed; }
            else       { effS0[i] = es; effD0[i] = ed; }
        }
        return;
    }
    int cb = b - 512;
    int convB = (N * 32 + 255) / 256;     // 8 floats per thread
    if (cb < convB) {
        int i = cb * 256 + t;
        if (i >= N * 32) return;
        float4 v0 = *(const float4*)(x + i * 8);
        float4 v1 = *(const float4*)(x + i * 8 + 4);
        ushort4 h0, l0, h1, l1;
        split_bf(v0.x, h0.x, l0.x);
        split_bf(v0.y, h0.y, l0.y);
        split_bf(v0.z, h0.z, l0.z);
        split_bf(v0.w, h0.w, l0.w);
        split_bf(v1.x, h1.x, l1.x);
        split_bf(v1.y, h1.y, l1.y);
        split_bf(v1.z, h1.z, l1.z);
        split_bf(v1.w, h1.w, l1.w);
        *(ushort4*)(xhi + i * 8) = h0;
        *(ushort4*)(xhi + i * 8 + 4) = h1;
        *(ushort4*)(xlo + i * 8) = l0;
        *(ushort4*)(xlo + i * 8 + 4) = l1;
        return;
    }
    // ---- cnt zero (replaces hipMemsetAsync; consumed by gemm0's fill tail) ----
    int i = (cb - convB) * 256 + t;
    if (i < 10016) cnt[i] = 0;
}

// ---------- MFMA GEMM + fused attention scores; B-tile staged in LDS ----------
// block = 512 threads = 8 waves sharing one 64-col n-tile; wave w owns rows
// m0 = by*128 + w*16. B staged in MFMA-fragment order -> conflict-free ds_read_b128.
// grid = (4, ceil(M/128)).
// FILL=1 (layer 0): append ELL fill tail (cnt zeroed by preceding prep dispatch;
// consumed by the following agg dispatch — stream-ordered, no intra-kernel dep).
template<int FILL>
__global__ __launch_bounds__(512) void gemm_fused(
    const ushort_t* __restrict__ Ahi, const ushort_t* __restrict__ Alo,
    const ushort_t* __restrict__ Bhi, const ushort_t* __restrict__ Blo,
    const float* __restrict__ effS, const float* __restrict__ effD,
    ushort_t* __restrict__ Cb, float* __restrict__ ssrc, float* __restrict__ sdst,
    const int* __restrict__ ei, int E_real, int E_total,
    int* __restrict__ cnt, int* __restrict__ ell, int M)
{
    __shared__ ushort_t sBh[16384];   // 32 KB: hi fragments
    __shared__ ushort_t sBl[16384];   // 32 KB: lo fragments
    const int K = 256;
    int tid = threadIdx.x;
    int n0 = blockIdx.x * 64;

    // ---- stage B-tile (64 rows x 256 K, hi+lo) into fragment-ordered LDS ----
    // fragment addr for (row rr, k): t=rr>>4, l16=rr&15, kblk=k>>5, quad=(k>>3)&3
    //   dst = (((t*8 + kblk)*4 + quad)*16 + l16)*8
    const ushort_t* srcH = Bhi + (size_t)n0 * K;
    const ushort_t* srcL = Blo + (size_t)n0 * K;
    #pragma unroll
    for (int c = 0; c < 4; c++) {
        int g  = c * 512 + tid;        // chunk id 0..2047 (8 shorts each)
        int rr = g >> 5;               // row 0..63
        int ch = g & 31;               // 8-short chunk within row
        int kblk = ch >> 2, quad = ch & 3;
        int tt = rr >> 4, l16r = rr & 15;
        int dst = (((tt * 8 + kblk) * 4 + quad) * 16 + l16r) * 8;
        *(bf16x8*)&sBh[dst] = *(const bf16x8*)(srcH + rr * K + ch * 8);
        *(bf16x8*)&sBl[dst] = *(const bf16x8*)(srcL + rr * K + ch * 8);
    }
    __syncthreads();

    int w = tid >> 6;
    int lane = tid & 63;
    int quad = lane >> 4;
    int l16 = lane & 15;
    int m0 = blockIdx.y * 128 + w * 16;
    int mr = m0 + l16; if (mr >= M) mr = M - 1;

    const ushort_t* ah = Ahi + mr * K + quad * 8;
    const ushort_t* al = Alo + mr * K + quad * 8;

    f32x4 acc[4] = {};
    #pragma unroll
    for (int kb = 0; kb < 8; kb++) {
        bf16x8 a_hi = *(const bf16x8*)(ah + kb * 32);
        bf16x8 a_lo = *(const bf16x8*)(al + kb * 32);
        #pragma unroll
        for (int t = 0; t < 4; t++) {
            int off = (((t * 8 + kb) * 4 + quad) * 16 + l16) * 8;
            bf16x8 b_hi = *(const bf16x8*)&sBh[off];
            bf16x8 b_lo = *(const bf16x8*)&sBl[off];
            acc[t] = __builtin_amdgcn_mfma_f32_16x16x32_bf16(a_hi, b_hi, acc[t], 0, 0, 0);
            acc[t] = __builtin_amdgcn_mfma_f32_16x16x32_bf16(a_hi, b_lo, acc[t], 0, 0, 0);
            acc[t] = __builtin_amdgcn_mfma_f32_16x16x32_bf16(a_lo, b_hi, acc[t], 0, 0, 0);
        }
    }

    // ---- store C as bf16: C/D layout col = l16, row = quad*4 + reg ----
    #pragma unroll
    for (int t = 0; t < 4; t++) {
        #pragma unroll
        for (int r = 0; r < 4; r++) {
            int m = m0 + quad * 4 + r;
            if (m < M) Cb[m * 256 + n0 + t * 16 + l16] = f2bf(acc[t][r]);
        }
    }

    // ---- fused scores (fp32, from accumulators) ----
    int h0 = n0 >> 5;
    float vs[2][4], vd[2][4];
    #pragma unroll
    for (int g = 0; g < 2; g++) {
        float e0s = effS[n0 + 32 * g + l16];
        float e1s = effS[n0 + 32 * g + 16 + l16];
        float e0d = effD[n0 + 32 * g + l16];
        float e1d = effD[n0 + 32 * g + 16 + l16];
        #pragma unroll
        for (int r = 0; r < 4; r++) {
            vs[g][r] = acc[2 * g][r] * e0s + acc[2 * g + 1][r] * e1s;
            vd[g][r] = acc[2 * g][r] * e0d + acc[2 * g + 1][r] * e1d;
        }
    }
    #pragma unroll
    for (int m = 1; m <= 8; m <<= 1) {
        #pragma unroll
        for (int g = 0; g < 2; g++)
            #pragma unroll
            for (int r = 0; r < 4; r++) {
                vs[g][r] += __shfl_xor(vs[g][r], m);
                vd[g][r] += __shfl_xor(vd[g][r], m);
            }
    }
    if (l16 == 0) {
        #pragma unroll
        for (int g = 0; g < 2; g++)
            #pragma unroll
            for (int r = 0; r < 4; r++) {
                int m = m0 + quad * 4 + r;
                if (m < M) {
                    ssrc[m * 8 + h0 + g] = vs[g][r];
                    sdst[m * 8 + h0 + g] = vd[g][r];
                }
            }
    }

    // ---- ELL fill tail (layer 0 only): independent of the work above ----
    if (FILL) {
        int stride = gridDim.x * gridDim.y * 512;
        int base = (blockIdx.y * gridDim.x + blockIdx.x) * 512 + tid;
        for (int e = base; e < E_total; e += stride) {
            int s, d;
            if (e < E_real) { s = ei[e]; d = ei[E_real + e]; }
            else            { s = d = e - E_real; }
            int pos = atomicAdd(&cnt[d], 1);
            if (pos < ELLW) ell[d * ELLW + pos] = s;
        }
    }
}

// ---------- gather-aggregate over ELL: 2 edges/wave-step, 16B loads ----------
// one wave per node. lanes 0-31 take edge 2p, lanes 32-63 take edge 2p+1;
// each lane covers 8 channels (one bf16x8 = 16B load).
// mode 1: ELU -> bf16 hi/lo 256ch; mode 2: head-mean -> 32ch fp32
__global__ __launch_bounds__(256) void ell_agg(const int* __restrict__ cnt,
                                               const int* __restrict__ ell,
                                               const ushort_t* __restrict__ xpb,
                                               const float* __restrict__ ssrc,
                                               const float* __restrict__ sdst,
                                               float* __restrict__ out,
                                               ushort_t* __restrict__ ohi,
                                               ushort_t* __restrict__ olo,
                                               int N, int mode)
{
    __shared__ int sidx[4][ELLW];
    int gid = blockIdx.x * blockDim.x + threadIdx.x;
    int d = gid >> 6;
    if (d >= N) return;
    int w = threadIdx.x >> 6;
    int lane = threadIdx.x & 63;
    int eo = lane >> 5;          // which edge of the pair this half-wave owns
    int l32 = lane & 31;         // channel-chunk id: ch = l32*8 .. +8
    int h = l32 >> 2;            // head for these 8 channels
    float ssrc_h = ssrc[d * 8 + h];
    int end = cnt[d]; if (end > ELLW) end = ELLW;
    const int* row = ell + d * ELLW;
    sidx[w][lane] = row[lane < end ? lane : 0];

    float acc[8] = {};
    float den = 0.f;
    for (int i = 0; i < end; i += 8) {       // 8 edges = 4 pair-steps per iter
        int idx[4];
        #pragma unroll
        for (int pp = 0; pp < 4; pp++) {
            int ii = i + 2 * pp + eo;
            idx[pp] = sidx[w][ii < end ? ii : 0];
        }
        float t4[4];
        #pragma unroll
        for (int pp = 0; pp < 4; pp++) t4[pp] = sdst[idx[pp] * 8 + h];
        bf16x8 v[4];
        #pragma unroll
        for (int pp = 0; pp < 4; pp++)
            v[pp] = *(const bf16x8*)(xpb + idx[pp] * 256 + l32 * 8);
        #pragma unroll
        for (int pp = 0; pp < 4; pp++) {
            int ii = i + 2 * pp + eo;
            float al = ssrc_h + t4[pp];
            al = al > 0.f ? al : NEG_SLOPE * al;
            float wgt = (ii < end) ? __expf(al) : 0.f;
            den += wgt;
            #pragma unroll
            for (int j = 0; j < 8; j++)
                acc[j] += bf2f((ushort_t)v[pp][j]) * wgt;
        }
    }
    // merge the two edge-halves (lanes l and l+32 hold the same channels)
    #pragma unroll
    for (int j = 0; j < 8; j++) acc[j] += __shfl_xor(acc[j], 32);
    den += __shfl_xor(den, 32);
    float inv = 1.f / den;
    #pragma unroll
    for (int j = 0; j < 8; j++) acc[j] *= inv;

    if (mode == 2) {
        #pragma unroll
        for (int m = 4; m <= 16; m <<= 1)
            #pragma unroll
            for (int j = 0; j < 8; j++) acc[j] += __shfl_xor(acc[j], m);
        if (lane < 4) {
            float4 r0 = { acc[0] * 0.125f, acc[1] * 0.125f, acc[2] * 0.125f, acc[3] * 0.125f };
            float4 r1 = { acc[4] * 0.125f, acc[5] * 0.125f, acc[6] * 0.125f, acc[7] * 0.125f };
            *(float4*)(out + d * 32 + l32 * 8) = r0;
            *(float4*)(out + d * 32 + l32 * 8 + 4) = r1;
        }
        return;
    }
    #pragma unroll
    for (int j = 0; j < 8; j++)
        acc[j] = acc[j] > 0.f ? acc[j] : (__expf(acc[j]) - 1.f);
    if (eo == 0) {
        ushort_t hs[8], ls[8];
        #pragma unroll
        for (int j = 0; j < 8; j++) split_bf(acc[j], hs[j], ls[j]);
        *(ushort4*)(ohi + d * 256 + l32 * 8)     = *(ushort4*)&hs[0];
        *(ushort4*)(ohi + d * 256 + l32 * 8 + 4) = *(ushort4*)&hs[4];
        *(ushort4*)(olo + d * 256 + l32 * 8)     = *(ushort4*)&ls[0];
        *(ushort4*)(olo + d * 256 + l32 * 8 + 4) = *(ushort4*)&ls[4];
    }
}

extern "C" void kernel_launch(void* const* d_in, const int* in_sizes, int n_in,
                              void* d_out, int out_size, void* d_ws, size_t ws_size,
                              hipStream_t stream)
{
    const float* x  = (const float*)d_in[0];
    const int*   ei = (const int*)d_in[1];
    const float* W0 = (const float*)d_in[2];
    const float* A0 = (const float*)d_in[3];
    const float* B0 = (const float*)d_in[4];
    const float* att_s0 = (const float*)d_in[5];
    const float* att_d0 = (const float*)d_in[6];
    const float* As0 = (const float*)d_in[7];
    const float* Bs0 = (const float*)d_in[8];
    const float* Ad0 = (const float*)d_in[9];
    const float* Bd0 = (const float*)d_in[10];
    const float* W1 = (const float*)d_in[11];
    const float* A1 = (const float*)d_in[12];
    const float* B1 = (const float*)d_in[13];
    const float* att_s1 = (const float*)d_in[14];
    const float* att_d1 = (const float*)d_in[15];
    const float* As1 = (const float*)d_in[16];
    const float* Bs1 = (const float*)d_in[17];
    const float* Ad1 = (const float*)d_in[18];
    const float* Bd1 = (const float*)d_in[19];

    const int N = in_sizes[0] / 256;      // 10000
    const int E_real = in_sizes[1] / 2;   // 160000
    const int E_total = E_real + N;       // 170000

    // ---- workspace layout ----
    ushort_t* whi0 = (ushort_t*)d_ws;        // 65536 each
    ushort_t* wlo0 = whi0 + 65536;
    ushort_t* whi1 = wlo0 + 65536;
    ushort_t* wlo1 = whi1 + 65536;
    ushort_t* xhi  = wlo1 + 65536;           // N*256
    ushort_t* xlo  = xhi + 2560000;
    ushort_t* hbhi = xlo + 2560000;
    ushort_t* hblo = hbhi + 2560000;
    ushort_t* xpb  = hblo + 2560000;         // N*256 bf16 projected features
    float* effS0 = (float*)(xpb + 2560000);
    float* effD0 = effS0 + 256;
    float* effS1 = effD0 + 256;
    float* effD1 = effS1 + 256;
    float* ssrc  = effD1 + 256;              // N*8
    float* sdst  = ssrc + 80000;
    int* cnt = (int*)(sdst + 80000);         // 10016
    int* ell = cnt + 10016;                  // N*ELLW

    // ---- fused prep: weights + x split + cnt zero (no memset dispatch) ----
    int convB = (N * 32 + 255) / 256;
    int cntB  = (10016 + 255) / 256;
    prep_all<<<512 + convB + cntB, 256, 0, stream>>>(
        W0, A0, B0, att_s0, att_d0, As0, Bs0, Ad0, Bd0,
        W1, A1, B1, att_s1, att_d1, As1, Bs1, Ad1, Bd1,
        whi0, wlo0, whi1, wlo1, effS0, effD0, effS1, effD1,
        x, xhi, xlo, cnt, N);

    dim3 gg(4, (N + 127) / 128);
    int aggBlocks = (N * 64 + 255) / 256;

    // ---------------- layer 0 (gemm0 carries the ELL fill tail) ----------------
    gemm_fused<1><<<gg, 512, 0, stream>>>(xhi, xlo, whi0, wlo0, effS0, effD0,
                                          xpb, ssrc, sdst,
                                          ei, E_real, E_total, cnt, ell, N);
    ell_agg<<<aggBlocks, 256, 0, stream>>>(cnt, ell, xpb, ssrc, sdst,
                                           nullptr, hbhi, hblo, N, 1);

    // ---------------- layer 1 ----------------
    gemm_fused<0><<<gg, 512, 0, stream>>>(hbhi, hblo, whi1, wlo1, effS1, effD1,
                                          xpb, ssrc, sdst,
                                          nullptr, 0, 0, nullptr, nullptr, N);
    ell_agg<<<aggBlocks, 256, 0, stream>>>(cnt, ell, xpb, ssrc, sdst,
                                           (float*)d_out, nullptr, nullptr, N, 2);
}

// Round 6
// 158.957 us; speedup vs baseline: 2.3970x; 1.0261x over previous
//
#include <hip/hip_runtime.h>

#define LORA_SCALE 4.0f
#define ATT_SCALE 8.0f
#define NEG_SLOPE 0.2f
#define ELLW 64

typedef __attribute__((ext_vector_type(8))) short bf16x8;
typedef __attribute__((ext_vector_type(4))) float f32x4;
typedef unsigned short ushort_t;
typedef unsigned int uint_t;

__device__ inline ushort_t f2bf(float f) {
    uint_t u = __float_as_uint(f);
    u += 0x7fff + ((u >> 16) & 1);     // RNE
    return (ushort_t)(u >> 16);
}
__device__ inline float bf2f(ushort_t h) {
    return __uint_as_float(((uint_t)h) << 16);
}
__device__ inline void split_bf(float f, ushort_t& h, ushort_t& l) {
    h = f2bf(f);
    l = f2bf(f - bf2f(h));
}

// ---------- prep: weights(2 layers) hi/lo + att-eff + cnt zero ----------
// (x-split moved into gemm0's A-path; ELL fill lives in gemm0's tail)
__global__ void prep_all(const float* __restrict__ W0, const float* __restrict__ A0,
                         const float* __restrict__ B0,
                         const float* __restrict__ att_s0, const float* __restrict__ att_d0,
                         const float* __restrict__ As0, const float* __restrict__ Bs0,
                         const float* __restrict__ Ad0, const float* __restrict__ Bd0,
                         const float* __restrict__ W1, const float* __restrict__ A1,
                         const float* __restrict__ B1,
                         const float* __restrict__ att_s1, const float* __restrict__ att_d1,
                         const float* __restrict__ As1, const float* __restrict__ Bs1,
                         const float* __restrict__ Ad1, const float* __restrict__ Bd1,
                         ushort_t* __restrict__ whi0, ushort_t* __restrict__ wlo0,
                         ushort_t* __restrict__ whi1, ushort_t* __restrict__ wlo1,
                         float* __restrict__ effS0, float* __restrict__ effD0,
                         float* __restrict__ effS1, float* __restrict__ effD1,
                         int* __restrict__ cnt, int N)
{
    int b = blockIdx.x;
    int t = threadIdx.x;
    if (b < 512) {
        int layer = b >> 8;
        int i = (b & 255) * 256 + t;
        const float* W = layer ? W1 : W0;
        const float* A = layer ? A1 : A0;
        const float* B = layer ? B1 : B0;
        int r = i >> 8, c = i & 255;
        float acc = W[i];
        #pragma unroll
        for (int k = 0; k < 8; k++) acc += LORA_SCALE * B[r * 8 + k] * A[k * 256 + c];
        ushort_t h, l;
        split_bf(acc, h, l);
        if (layer) { whi1[i] = h; wlo1[i] = l; }
        else       { whi0[i] = h; wlo0[i] = l; }
        if (i < 256) {
            int c2 = i & 31;
            const float* as_ = layer ? att_s1 : att_s0;
            const float* ad_ = layer ? att_d1 : att_d0;
            const float* As = layer ? As1 : As0;
            const float* Bs = layer ? Bs1 : Bs0;
            const float* Ad = layer ? Ad1 : Ad0;
            const float* Bd = layer ? Bd1 : Bd0;
            float es = as_[i], ed = ad_[i];
            #pragma unroll
            for (int k = 0; k < 4; k++) {
                es += ATT_SCALE * Bs[k] * As[k * 32 + c2];
                ed += ATT_SCALE * Bd[k] * Ad[k * 32 + c2];
            }
            if (layer) { effS1[i] = es; effD1[i] = ed; }
            else       { effS0[i] = es; effD0[i] = ed; }
        }
        return;
    }
    // ---- cnt zero (consumed by gemm0's fill tail) ----
    int i = (b - 512) * 256 + t;
    if (i < 10016) cnt[i] = 0;
}

// ---------- MFMA GEMM + fused attention scores; B-tile staged in LDS ----------
// block = 512 threads = 8 waves sharing one 64-col n-tile; wave w owns rows
// m0 = by*128 + w*16. B staged in MFMA-fragment order -> conflict-free ds_read_b128.
// grid = (4, ceil(M/128)).
// XSPLIT=1: A-operand read as fp32 and split to bf16 hi/lo in-register
//           (bit-identical to prep's split; deletes the xhi/xlo round-trip).
// FILL=1:   append ELL fill tail (cnt zeroed by preceding prep dispatch;
//           consumed by the following agg dispatch — stream-ordered).
template<int FILL, int XSPLIT>
__global__ __launch_bounds__(512) void gemm_fused(
    const float* __restrict__ Xf,
    const ushort_t* __restrict__ Ahi, const ushort_t* __restrict__ Alo,
    const ushort_t* __restrict__ Bhi, const ushort_t* __restrict__ Blo,
    const float* __restrict__ effS, const float* __restrict__ effD,
    ushort_t* __restrict__ Cb, float* __restrict__ ssrc, float* __restrict__ sdst,
    const int* __restrict__ ei, int E_real, int E_total,
    int* __restrict__ cnt, int* __restrict__ ell, int M)
{
    __shared__ ushort_t sBh[16384];   // 32 KB: hi fragments
    __shared__ ushort_t sBl[16384];   // 32 KB: lo fragments
    const int K = 256;
    int tid = threadIdx.x;
    int n0 = blockIdx.x * 64;

    // ---- stage B-tile (64 rows x 256 K, hi+lo) into fragment-ordered LDS ----
    // fragment addr for (row rr, k): t=rr>>4, l16=rr&15, kblk=k>>5, quad=(k>>3)&3
    //   dst = (((t*8 + kblk)*4 + quad)*16 + l16)*8
    const ushort_t* srcH = Bhi + (size_t)n0 * K;
    const ushort_t* srcL = Blo + (size_t)n0 * K;
    #pragma unroll
    for (int c = 0; c < 4; c++) {
        int g  = c * 512 + tid;        // chunk id 0..2047 (8 shorts each)
        int rr = g >> 5;               // row 0..63
        int ch = g & 31;               // 8-short chunk within row
        int kblk = ch >> 2, quad = ch & 3;
        int tt = rr >> 4, l16r = rr & 15;
        int dst = (((tt * 8 + kblk) * 4 + quad) * 16 + l16r) * 8;
        *(bf16x8*)&sBh[dst] = *(const bf16x8*)(srcH + rr * K + ch * 8);
        *(bf16x8*)&sBl[dst] = *(const bf16x8*)(srcL + rr * K + ch * 8);
    }
    __syncthreads();

    int w = tid >> 6;
    int lane = tid & 63;
    int quad = lane >> 4;
    int l16 = lane & 15;
    int m0 = blockIdx.y * 128 + w * 16;
    int mr = m0 + l16; if (mr >= M) mr = M - 1;

    const float* xrow = XSPLIT ? (Xf + (size_t)mr * K + quad * 8) : nullptr;
    const ushort_t* ah = XSPLIT ? nullptr : (Ahi + (size_t)mr * K + quad * 8);
    const ushort_t* al = XSPLIT ? nullptr : (Alo + (size_t)mr * K + quad * 8);

    f32x4 acc[4] = {};
    #pragma unroll
    for (int kb = 0; kb < 8; kb++) {
        bf16x8 a_hi, a_lo;
        if (XSPLIT) {
            float4 f0 = *(const float4*)(xrow + kb * 32);
            float4 f1 = *(const float4*)(xrow + kb * 32 + 4);
            float fv[8] = { f0.x, f0.y, f0.z, f0.w, f1.x, f1.y, f1.z, f1.w };
            #pragma unroll
            for (int j = 0; j < 8; j++) {
                ushort_t hh, ll;
                split_bf(fv[j], hh, ll);
                a_hi[j] = (short)hh;
                a_lo[j] = (short)ll;
            }
        } else {
            a_hi = *(const bf16x8*)(ah + kb * 32);
            a_lo = *(const bf16x8*)(al + kb * 32);
        }
        #pragma unroll
        for (int t = 0; t < 4; t++) {
            int off = (((t * 8 + kb) * 4 + quad) * 16 + l16) * 8;
            bf16x8 b_hi = *(const bf16x8*)&sBh[off];
            bf16x8 b_lo = *(const bf16x8*)&sBl[off];
            acc[t] = __builtin_amdgcn_mfma_f32_16x16x32_bf16(a_hi, b_hi, acc[t], 0, 0, 0);
            acc[t] = __builtin_amdgcn_mfma_f32_16x16x32_bf16(a_hi, b_lo, acc[t], 0, 0, 0);
            acc[t] = __builtin_amdgcn_mfma_f32_16x16x32_bf16(a_lo, b_hi, acc[t], 0, 0, 0);
        }
    }

    // ---- store C as bf16: C/D layout col = l16, row = quad*4 + reg ----
    #pragma unroll
    for (int t = 0; t < 4; t++) {
        #pragma unroll
        for (int r = 0; r < 4; r++) {
            int m = m0 + quad * 4 + r;
            if (m < M) Cb[m * 256 + n0 + t * 16 + l16] = f2bf(acc[t][r]);
        }
    }

    // ---- fused scores (fp32, from accumulators) ----
    int h0 = n0 >> 5;
    float vs[2][4], vd[2][4];
    #pragma unroll
    for (int g = 0; g < 2; g++) {
        float e0s = effS[n0 + 32 * g + l16];
        float e1s = effS[n0 + 32 * g + 16 + l16];
        float e0d = effD[n0 + 32 * g + l16];
        float e1d = effD[n0 + 32 * g + 16 + l16];
        #pragma unroll
        for (int r = 0; r < 4; r++) {
            vs[g][r] = acc[2 * g][r] * e0s + acc[2 * g + 1][r] * e1s;
            vd[g][r] = acc[2 * g][r] * e0d + acc[2 * g + 1][r] * e1d;
        }
    }
    #pragma unroll
    for (int m = 1; m <= 8; m <<= 1) {
        #pragma unroll
        for (int g = 0; g < 2; g++)
            #pragma unroll
            for (int r = 0; r < 4; r++) {
                vs[g][r] += __shfl_xor(vs[g][r], m);
                vd[g][r] += __shfl_xor(vd[g][r], m);
            }
    }
    if (l16 == 0) {
        #pragma unroll
        for (int g = 0; g < 2; g++)
            #pragma unroll
            for (int r = 0; r < 4; r++) {
                int m = m0 + quad * 4 + r;
                if (m < M) {
                    ssrc[m * 8 + h0 + g] = vs[g][r];
                    sdst[m * 8 + h0 + g] = vd[g][r];
                }
            }
    }

    // ---- ELL fill tail (layer 0 only): independent of the work above ----
    if (FILL) {
        int stride = gridDim.x * gridDim.y * 512;
        int base = (blockIdx.y * gridDim.x + blockIdx.x) * 512 + tid;
        for (int e = base; e < E_total; e += stride) {
            int s, d;
            if (e < E_real) { s = ei[e]; d = ei[E_real + e]; }
            else            { s = d = e - E_real; }
            int pos = atomicAdd(&cnt[d], 1);
            if (pos < ELLW) ell[d * ELLW + pos] = s;
        }
    }
}

// ---------- gather-aggregate over ELL: 2 edges/wave-step, 16B loads ----------
// one wave per node. lanes 0-31 take edge 2p, lanes 32-63 take edge 2p+1;
// each lane covers 8 channels (one bf16x8 = 16B load).
// mode 1: ELU -> bf16 hi/lo 256ch; mode 2: head-mean -> 32ch fp32
__global__ __launch_bounds__(256) void ell_agg(const int* __restrict__ cnt,
                                               const int* __restrict__ ell,
                                               const ushort_t* __restrict__ xpb,
                                               const float* __restrict__ ssrc,
                                               const float* __restrict__ sdst,
                                               float* __restrict__ out,
                                               ushort_t* __restrict__ ohi,
                                               ushort_t* __restrict__ olo,
                                               int N, int mode)
{
    __shared__ int sidx[4][ELLW];
    int gid = blockIdx.x * blockDim.x + threadIdx.x;
    int d = gid >> 6;
    if (d >= N) return;
    int w = threadIdx.x >> 6;
    int lane = threadIdx.x & 63;
    int eo = lane >> 5;          // which edge of the pair this half-wave owns
    int l32 = lane & 31;         // channel-chunk id: ch = l32*8 .. +8
    int h = l32 >> 2;            // head for these 8 channels
    float ssrc_h = ssrc[d * 8 + h];
    int end = cnt[d]; if (end > ELLW) end = ELLW;
    const int* row = ell + d * ELLW;
    sidx[w][lane] = row[lane < end ? lane : 0];

    float acc[8] = {};
    float den = 0.f;
    for (int i = 0; i < end; i += 8) {       // 8 edges = 4 pair-steps per iter
        int idx[4];
        #pragma unroll
        for (int pp = 0; pp < 4; pp++) {
            int ii = i + 2 * pp + eo;
            idx[pp] = sidx[w][ii < end ? ii : 0];
        }
        float t4[4];
        #pragma unroll
        for (int pp = 0; pp < 4; pp++) t4[pp] = sdst[idx[pp] * 8 + h];
        bf16x8 v[4];
        #pragma unroll
        for (int pp = 0; pp < 4; pp++)
            v[pp] = *(const bf16x8*)(xpb + idx[pp] * 256 + l32 * 8);
        #pragma unroll
        for (int pp = 0; pp < 4; pp++) {
            int ii = i + 2 * pp + eo;
            float al = ssrc_h + t4[pp];
            al = al > 0.f ? al : NEG_SLOPE * al;
            float wgt = (ii < end) ? __expf(al) : 0.f;
            den += wgt;
            #pragma unroll
            for (int j = 0; j < 8; j++)
                acc[j] += bf2f((ushort_t)v[pp][j]) * wgt;
        }
    }
    // merge the two edge-halves (lanes l and l+32 hold the same channels)
    #pragma unroll
    for (int j = 0; j < 8; j++) acc[j] += __shfl_xor(acc[j], 32);
    den += __shfl_xor(den, 32);
    float inv = 1.f / den;
    #pragma unroll
    for (int j = 0; j < 8; j++) acc[j] *= inv;

    if (mode == 2) {
        #pragma unroll
        for (int m = 4; m <= 16; m <<= 1)
            #pragma unroll
            for (int j = 0; j < 8; j++) acc[j] += __shfl_xor(acc[j], m);
        if (lane < 4) {
            float4 r0 = { acc[0] * 0.125f, acc[1] * 0.125f, acc[2] * 0.125f, acc[3] * 0.125f };
            float4 r1 = { acc[4] * 0.125f, acc[5] * 0.125f, acc[6] * 0.125f, acc[7] * 0.125f };
            *(float4*)(out + d * 32 + l32 * 8) = r0;
            *(float4*)(out + d * 32 + l32 * 8 + 4) = r1;
        }
        return;
    }
    #pragma unroll
    for (int j = 0; j < 8; j++)
        acc[j] = acc[j] > 0.f ? acc[j] : (__expf(acc[j]) - 1.f);
    if (eo == 0) {
        ushort_t hs[8], ls[8];
        #pragma unroll
        for (int j = 0; j < 8; j++) split_bf(acc[j], hs[j], ls[j]);
        *(ushort4*)(ohi + d * 256 + l32 * 8)     = *(ushort4*)&hs[0];
        *(ushort4*)(ohi + d * 256 + l32 * 8 + 4) = *(ushort4*)&hs[4];
        *(ushort4*)(olo + d * 256 + l32 * 8)     = *(ushort4*)&ls[0];
        *(ushort4*)(olo + d * 256 + l32 * 8 + 4) = *(ushort4*)&ls[4];
    }
}

extern "C" void kernel_launch(void* const* d_in, const int* in_sizes, int n_in,
                              void* d_out, int out_size, void* d_ws, size_t ws_size,
                              hipStream_t stream)
{
    const float* x  = (const float*)d_in[0];
    const int*   ei = (const int*)d_in[1];
    const float* W0 = (const float*)d_in[2];
    const float* A0 = (const float*)d_in[3];
    const float* B0 = (const float*)d_in[4];
    const float* att_s0 = (const float*)d_in[5];
    const float* att_d0 = (const float*)d_in[6];
    const float* As0 = (const float*)d_in[7];
    const float* Bs0 = (const float*)d_in[8];
    const float* Ad0 = (const float*)d_in[9];
    const float* Bd0 = (const float*)d_in[10];
    const float* W1 = (const float*)d_in[11];
    const float* A1 = (const float*)d_in[12];
    const float* B1 = (const float*)d_in[13];
    const float* att_s1 = (const float*)d_in[14];
    const float* att_d1 = (const float*)d_in[15];
    const float* As1 = (const float*)d_in[16];
    const float* Bs1 = (const float*)d_in[17];
    const float* Ad1 = (const float*)d_in[18];
    const float* Bd1 = (const float*)d_in[19];

    const int N = in_sizes[0] / 256;      // 10000
    const int E_real = in_sizes[1] / 2;   // 160000
    const int E_total = E_real + N;       // 170000

    // ---- workspace layout ----
    ushort_t* whi0 = (ushort_t*)d_ws;        // 65536 each
    ushort_t* wlo0 = whi0 + 65536;
    ushort_t* whi1 = wlo0 + 65536;
    ushort_t* wlo1 = whi1 + 65536;
    ushort_t* hbhi = wlo1 + 65536;           // N*256 each
    ushort_t* hblo = hbhi + 2560000;
    ushort_t* xpb  = hblo + 2560000;         // N*256 bf16 projected features
    float* effS0 = (float*)(xpb + 2560000);
    float* effD0 = effS0 + 256;
    float* effS1 = effD0 + 256;
    float* effD1 = effS1 + 256;
    float* ssrc  = effD1 + 256;              // N*8
    float* sdst  = ssrc + 80000;
    int* cnt = (int*)(sdst + 80000);         // 10016
    int* ell = cnt + 10016;                  // N*ELLW

    // ---- prep: weights + att-eff + cnt zero ----
    int cntB = (10016 + 255) / 256;
    prep_all<<<512 + cntB, 256, 0, stream>>>(
        W0, A0, B0, att_s0, att_d0, As0, Bs0, Ad0, Bd0,
        W1, A1, B1, att_s1, att_d1, As1, Bs1, Ad1, Bd1,
        whi0, wlo0, whi1, wlo1, effS0, effD0, effS1, effD1,
        cnt, N);

    dim3 gg(4, (N + 127) / 128);
    int aggBlocks = (N * 64 + 255) / 256;

    // ---------------- layer 0 (x split in-register; carries ELL fill tail) ----------------
    gemm_fused<1, 1><<<gg, 512, 0, stream>>>(x, nullptr, nullptr,
                                             whi0, wlo0, effS0, effD0,
                                             xpb, ssrc, sdst,
                                             ei, E_real, E_total, cnt, ell, N);
    ell_agg<<<aggBlocks, 256, 0, stream>>>(cnt, ell, xpb, ssrc, sdst,
                                           nullptr, hbhi, hblo, N, 1);

    // ---------------- layer 1 ----------------
    gemm_fused<0, 0><<<gg, 512, 0, stream>>>(nullptr, hbhi, hblo,
                                             whi1, wlo1, effS1, effD1,
                                             xpb, ssrc, sdst,
                                             nullptr, 0, 0, nullptr, nullptr, N);
    ell_agg<<<aggBlocks, 256, 0, stream>>>(cnt, ell, xpb, ssrc, sdst,
                                           (float*)d_out, nullptr, nullptr, N, 2);
}